// Round 1
// baseline (43842.145 us; speedup 1.0000x reference)
//
#include <hip/hip_runtime.h>
#include <math.h>

// Problem constants
#define Bsz  512
#define Tlen 1024
#define Din  128
#define Hdim 256
// gates dim = 4*H = 1024

// Workspace layout (floats), S = Bsz*Hdim = 131072:
// [0..S)   h1 buf0      [S..2S)  h1 buf1
// [2S..3S) h2 buf0      [3S..4S) h2 buf1
// [4S..5S) c1           [5S..6S) c2
// Total 6*S*4 = 3 MB

__device__ __forceinline__ float sig_(float v) { return 1.0f / (1.0f + __expf(-v)); }

// Phase kernel: blocks 0..127 = layer1 step p; blocks 128..255 = layer2 step p-1.
// Per block: 64 batch rows x 16 hidden units (= 64 gate columns: f,i,g,o strips of 16).
__global__ __launch_bounds__(256) void lstm_phase(
    const float* __restrict__ x,
    const float* __restrict__ W1, const float* __restrict__ b1,
    const float* __restrict__ W2, const float* __restrict__ b2,
    float* __restrict__ ws, int p)
{
    const int S = Bsz * Hdim;
    const bool is_l1 = (blockIdx.x < 128);
    if (is_l1 && p >= Tlen) return;   // layer1 idle at final phase
    if (!is_l1 && p == 0) return;     // layer2 idle at first phase

    const int lid = blockIdx.x & 127;
    const int b0  = (lid >> 4) * 64;   // batch tile start
    const int hs  = (lid & 15) * 16;   // hidden-slice start

    float* h1b0 = ws;           float* h1b1 = ws + S;
    float* h2b0 = ws + 2 * S;   float* h2b1 = ws + 3 * S;
    float* c1   = ws + 4 * S;   float* c2   = ws + 5 * S;

    const float* h1_old = ((p + 1) & 1) ? h1b1 : h1b0; // h1 state after step p-1
    const float* h2_old = ((p + 1) & 1) ? h2b1 : h2b0; // h2 state after step p-2

    const float* W;  const float* bias;
    float* cbuf;     float* hout;
    int K;
    if (is_l1) {
        W = W1; bias = b1; cbuf = c1; K = Din + Hdim;          // 384
        hout = (p & 1) ? h1b1 : h1b0;
    } else {
        W = W2; bias = b2; cbuf = c2; K = 2 * Hdim;            // 512
        hout = (p & 1) ? h2b1 : h2b0;
    }

    __shared__ float As[16][68];
    __shared__ float Bs[16][68];
    __shared__ float gsm[64][68];

    const int tid = threadIdx.x;
    const int tx = tid & 15, ty = tid >> 4;

    float acc[4][4];
#pragma unroll
    for (int r = 0; r < 4; ++r)
#pragma unroll
        for (int s = 0; s < 4; ++s) acc[r][s] = 0.0f;

    // A-tile loader indices: thread covers rows m, 4 consecutive k
    const int am  = tid >> 2;          // 0..63  (batch row within tile)
    const int ak0 = 4 * (tid & 3);     // 0,4,8,12 (k within 16-tile)
    // B-tile loader indices
    const int bkk = tid >> 4;          // 0..15 (k row within tile)
    const int bc0 = 4 * (tid & 15);    // 0..60 (local gate col, within one 16-strip)
    const int bg  = bc0 >> 4;          // gate index 0..3
    const int bj  = bc0 & 15;          // hidden offset within slice
    const size_t bcol = (size_t)bg * 256 + hs + bj;

    for (int k0 = 0; k0 < K; k0 += 16) {
        __syncthreads();
        // ---- stage A tile: A[b0+m][k0+ak0 .. +3]
        {
            const int k = k0 + ak0;
            float4 av;
            if (is_l1) {
                if (k < Din) {
                    av = *(const float4*)(x + (size_t)(b0 + am) * (Tlen * Din) + (size_t)p * Din + k);
                } else {
                    av = *(const float4*)(h1_old + (size_t)(b0 + am) * Hdim + (k - Din));
                }
            } else {
                if (k < Hdim) {
                    av = *(const float4*)(h1_old + (size_t)(b0 + am) * Hdim + k);
                } else {
                    av = *(const float4*)(h2_old + (size_t)(b0 + am) * Hdim + (k - Hdim));
                }
            }
            As[ak0 + 0][am] = av.x;
            As[ak0 + 1][am] = av.y;
            As[ak0 + 2][am] = av.z;
            As[ak0 + 3][am] = av.w;
        }
        // ---- stage B tile: W[k0+bkk][bcol .. +3]
        {
            float4 bv = *(const float4*)(W + (size_t)(k0 + bkk) * 1024 + bcol);
            *(float4*)&Bs[bkk][bc0] = bv;
        }
        __syncthreads();
        // ---- FMA
#pragma unroll
        for (int kk = 0; kk < 16; ++kk) {
            float4 a = *(const float4*)&As[kk][4 * ty];
            float4 b = *(const float4*)&Bs[kk][4 * tx];
            acc[0][0] += a.x * b.x; acc[0][1] += a.x * b.y; acc[0][2] += a.x * b.z; acc[0][3] += a.x * b.w;
            acc[1][0] += a.y * b.x; acc[1][1] += a.y * b.y; acc[1][2] += a.y * b.z; acc[1][3] += a.y * b.w;
            acc[2][0] += a.z * b.x; acc[2][1] += a.z * b.y; acc[2][2] += a.z * b.z; acc[2][3] += a.z * b.w;
            acc[3][0] += a.w * b.x; acc[3][1] += a.w * b.y; acc[3][2] += a.w * b.z; acc[3][3] += a.w * b.w;
        }
    }

    // ---- epilogue: gates -> LDS (+bias), then cell update
    __syncthreads();
    {
        const int c0 = 4 * tx;                       // local col base
        const int g  = c0 >> 4;
        const int j0 = c0 & 15;
        float4 bv = *(const float4*)(bias + (size_t)g * 256 + hs + j0);
#pragma unroll
        for (int r = 0; r < 4; ++r) {
            float4 v;
            v.x = acc[r][0] + bv.x;
            v.y = acc[r][1] + bv.y;
            v.z = acc[r][2] + bv.z;
            v.w = acc[r][3] + bv.w;
            *(float4*)&gsm[4 * ty + r][c0] = v;
        }
    }
    __syncthreads();
    {
        const int mb = tid >> 2;            // batch row within tile
        const int je = 4 * (tid & 3);       // hidden offset base
#pragma unroll
        for (int u = 0; u < 4; ++u) {
            const int j = je + u;
            float fg = gsm[mb][j];
            float ig = gsm[mb][16 + j];
            float gg = gsm[mb][32 + j];
            float og = gsm[mb][48 + j];
            const size_t gi = (size_t)(b0 + mb) * Hdim + hs + j;
            float cold = cbuf[gi];
            float cn = sig_(fg) * cold + sig_(ig) * tanhf(gg);
            cbuf[gi] = cn;
            hout[gi] = sig_(og) * tanhf(cn);
        }
    }
}

// Final projection: out[b] = h2[b,:] . Wout + bout
__global__ __launch_bounds__(256) void out_proj(
    const float* __restrict__ h2, const float* __restrict__ Wout,
    const float* __restrict__ bout, float* __restrict__ out)
{
    const int b    = blockIdx.x * 4 + (threadIdx.x >> 6);
    const int lane = threadIdx.x & 63;
    float4 h = *(const float4*)&h2[(size_t)b * Hdim + lane * 4];
    float4 w = *(const float4*)&Wout[lane * 4];
    float s = h.x * w.x + h.y * w.y + h.z * w.z + h.w * w.w;
#pragma unroll
    for (int off = 32; off > 0; off >>= 1) s += __shfl_down(s, off);
    if (lane == 0) out[b] = s + bout[0];
}

extern "C" void kernel_launch(void* const* d_in, const int* in_sizes, int n_in,
                              void* d_out, int out_size, void* d_ws, size_t ws_size,
                              hipStream_t stream)
{
    const float* x    = (const float*)d_in[0];
    const float* W1   = (const float*)d_in[1];
    const float* b1   = (const float*)d_in[2];
    const float* W2   = (const float*)d_in[3];
    const float* b2   = (const float*)d_in[4];
    const float* Wout = (const float*)d_in[5];
    const float* bout = (const float*)d_in[6];
    float* out = (float*)d_out;
    float* ws  = (float*)d_ws;

    const size_t S = (size_t)Bsz * Hdim;
    hipMemsetAsync(d_ws, 0, 6 * S * sizeof(float), stream);

    for (int p = 0; p <= Tlen; ++p) {
        lstm_phase<<<256, 256, 0, stream>>>(x, W1, b1, W2, b2, ws, p);
    }
    // h2 final state written at phase p=1024 -> parity 0 -> h2 buf0 = ws + 2S
    out_proj<<<128, 256, 0, stream>>>(ws + 2 * S, Wout, bout, out);
}

// Round 2
// 24053.613 us; speedup vs baseline: 1.8227x; 1.8227x over previous
//
#include <hip/hip_runtime.h>
#include <math.h>

#define PODS  8
#define Bsz   512
#define Tlen  1024
#define Din   128
#define Hdim  256

typedef __attribute__((ext_vector_type(8))) short  short8;
typedef __attribute__((ext_vector_type(4))) float  f32x4;

// ---------------- ws layout (bytes) ----------------
// [0,1024)                  : pod barrier counters, bar[pod*32] (zeroed)
// [1024, +1 MB)             : parity-1 h planes (zeroed): h1hi,h1lo,h2hi,h2lo each 512*256*2 B
// [+1 MB, +2 MB)            : parity-0 h planes (written before read)
// [2098176, +768 KB)        : W1-lo swizzled, per hs slab 48 KB
// [2884608, +1 MB)          : W2-lo swizzled, per hs slab 64 KB
#define WS_BAR    0
#define WS_H      1024
#define WS_WLO1   2098176
#define WS_WLO2   2884608
#define HPLANE    262144   // 512*256*2
#define ZERO_BYTES (1024 + 1048576)

__device__ __forceinline__ unsigned short f2bf(float f) {
    unsigned u = __float_as_uint(f);
    u += 0x7fffu + ((u >> 16) & 1u);
    return (unsigned short)(u >> 16);
}
__device__ __forceinline__ float bf2f(unsigned short s) {
    return __uint_as_float(((unsigned)s) << 16);
}
__device__ __forceinline__ float sigf(float x) { return 1.0f / (1.0f + __expf(-x)); }
__device__ __forceinline__ float tanh_(float x) {
    x = fminf(fmaxf(x, -15.0f), 15.0f);
    float e = __expf(2.0f * x);
    return (e - 1.0f) / (e + 1.0f);
}

// One phase of one layer for one wave (16 batch rows x 64 gate cols = 4 gates x 16 hidden).
// A = [x_t | h1_old] (L1) or [h1_cur | h2_old] (L2); split-bf16, 3 MFMAs per product.
template<bool IS_L1>
__device__ __forceinline__ void phase_compute(
    int step, int pod, int hs, int w, int lane,
    const float* __restrict__ x,
    const short8* __restrict__ whi,          // LDS, fragment order
    const short8* __restrict__ blo,          // global ws, fragment order
    const unsigned short* __restrict__ p1h, const unsigned short* __restrict__ p1l,
    const unsigned short* __restrict__ p2h, const unsigned short* __restrict__ p2l,
    unsigned short* __restrict__ ohi, unsigned short* __restrict__ olo,
    float* creg, const float* biasg)
{
    const int q = lane >> 4, n = lane & 15;
    const int rowA = pod * 64 + w * 16 + n;

    f32x4 acc[4];
#pragma unroll
    for (int g = 0; g < 4; ++g) {
        acc[g][0] = biasg[g]; acc[g][1] = biasg[g];
        acc[g][2] = biasg[g]; acc[g][3] = biasg[g];
    }

    constexpr int SPLITKS = IS_L1 ? 4 : 8;    // ksteps in part 1 (x / h1)
    constexpr int NKS     = IS_L1 ? 12 : 16;  // total ksteps (K=384 / 512)

    // ---- part 1: L1 -> x (fp32, convert+split), L2 -> h1 current (bf16 planes)
#pragma unroll 2
    for (int ks = 0; ks < SPLITKS; ++ks) {
        const int kk = ks * 32 + q * 8;
        short8 ah, al;
        if (IS_L1) {
            const float* xp = x + (size_t)rowA * (size_t)(Tlen * Din) + (size_t)step * Din + kk;
            f32x4 v0 = *(const f32x4*)xp;
            f32x4 v1 = *(const f32x4*)(xp + 4);
            float vv[8] = {v0[0], v0[1], v0[2], v0[3], v1[0], v1[1], v1[2], v1[3]};
#pragma unroll
            for (int j = 0; j < 8; ++j) {
                unsigned short h = f2bf(vv[j]);
                ah[j] = (short)h;
                al[j] = (short)f2bf(vv[j] - bf2f(h));
            }
        } else {
            ah = *(const short8*)(p1h + (size_t)rowA * Hdim + kk);
            al = *(const short8*)(p1l + (size_t)rowA * Hdim + kk);
        }
#pragma unroll
        for (int g = 0; g < 4; ++g) {
            short8 bh = whi[ks * 256 + g * 64 + lane];
            short8 bl = blo[ks * 256 + g * 64 + lane];
            acc[g] = __builtin_amdgcn_mfma_f32_16x16x32_bf16(ah, bh, acc[g], 0, 0, 0);
            acc[g] = __builtin_amdgcn_mfma_f32_16x16x32_bf16(al, bh, acc[g], 0, 0, 0);
            acc[g] = __builtin_amdgcn_mfma_f32_16x16x32_bf16(ah, bl, acc[g], 0, 0, 0);
        }
    }

    // ---- part 2: L1 -> h1_old, L2 -> h2_old
#pragma unroll 2
    for (int ks = SPLITKS; ks < NKS; ++ks) {
        const int kk = ks * 32 + q * 8;
        const int koff = kk - SPLITKS * 32;
        short8 ah = *(const short8*)(p2h + (size_t)rowA * Hdim + koff);
        short8 al = *(const short8*)(p2l + (size_t)rowA * Hdim + koff);
#pragma unroll
        for (int g = 0; g < 4; ++g) {
            short8 bh = whi[ks * 256 + g * 64 + lane];
            short8 bl = blo[ks * 256 + g * 64 + lane];
            acc[g] = __builtin_amdgcn_mfma_f32_16x16x32_bf16(ah, bh, acc[g], 0, 0, 0);
            acc[g] = __builtin_amdgcn_mfma_f32_16x16x32_bf16(al, bh, acc[g], 0, 0, 0);
            acc[g] = __builtin_amdgcn_mfma_f32_16x16x32_bf16(ah, bl, acc[g], 0, 0, 0);
        }
    }

    // ---- epilogue: per-lane cell update (f,i,g,o in same lane/reg), c in fp32 regs
#pragma unroll
    for (int r = 0; r < 4; ++r) {
        float fg = acc[0][r], ig = acc[1][r], gg = acc[2][r], og = acc[3][r];
        float cn = sigf(fg) * creg[r] + sigf(ig) * tanh_(gg);
        creg[r] = cn;
        float hv = sigf(og) * tanh_(cn);
        const int row = pod * 64 + w * 16 + q * 4 + r;
        const int ci  = hs * 16 + n;
        unsigned short hh = f2bf(hv);
        ohi[(size_t)row * Hdim + ci] = hh;
        olo[(size_t)row * Hdim + ci] = f2bf(hv - bf2f(hh));
    }
}

__global__ __launch_bounds__(256, 1) void lstm_persist(
    const float* __restrict__ x,
    const float* __restrict__ W1, const float* __restrict__ b1,
    const float* __restrict__ W2, const float* __restrict__ b2,
    const float* __restrict__ Wout, const float* __restrict__ bout,
    float* __restrict__ out, char* __restrict__ wsb)
{
    __shared__ short8 whi[4096];   // 64 KB: 16 ksteps x 4 gates x 64 lanes x 16 B

    const int tid    = threadIdx.x;
    const int pod    = blockIdx.x & 7;
    const int member = blockIdx.x >> 3;   // 0..31
    const bool is_l1 = (member < 16);
    const int hs     = member & 15;
    const int NKS    = is_l1 ? 12 : 16;
    const float* Wraw = is_l1 ? W1 : W2;
    const float* bias = is_l1 ? b1 : b2;

    short8* blo = (short8*)(wsb + (is_l1 ? (WS_WLO1 + (size_t)hs * 49152)
                                         : (WS_WLO2 + (size_t)hs * 65536)));

    // ---- init: swizzle W slice into fragment order: hi -> LDS, lo -> ws (global)
    for (int t = tid; t < NKS * 256; t += 256) {
        const int lane = t & 63, g = (t >> 6) & 3, ks = t >> 8;
        const int q = lane >> 4, n = lane & 15;
        const int col = g * 256 + hs * 16 + n;
        short8 hv, lv;
#pragma unroll
        for (int j = 0; j < 8; ++j) {
            float v = Wraw[(size_t)(ks * 32 + q * 8 + j) * 1024 + col];
            unsigned short h = f2bf(v);
            hv[j] = (short)h;
            lv[j] = (short)f2bf(v - bf2f(h));
        }
        whi[t] = hv;
        blo[t] = lv;
    }
    __syncthreads();   // drains vmem too: our blo writes are visible to this block

    const int w = tid >> 6, lane = tid & 63;
    const int n = lane & 15;
    float biasg[4];
#pragma unroll
    for (int g = 0; g < 4; ++g) biasg[g] = bias[g * 256 + hs * 16 + n];

    float creg[4] = {0.f, 0.f, 0.f, 0.f};
    unsigned* bar = (unsigned*)(wsb + WS_BAR) + pod * 32;

    auto plane = [&](int par, int idx) -> unsigned short* {
        return (unsigned short*)(wsb + WS_H + (size_t)(par ^ 1) * 1048576 + (size_t)idx * HPLANE);
    };

    for (int p = 0; p <= Tlen; ++p) {
        if (is_l1) {
            if (p < Tlen) {
                const int s = p;
                unsigned short* h1o_h = plane((s + 1) & 1, 0);
                unsigned short* h1o_l = plane((s + 1) & 1, 1);
                unsigned short* h1w_h = plane(s & 1, 0);
                unsigned short* h1w_l = plane(s & 1, 1);
                phase_compute<true>(s, pod, hs, w, lane, x, whi, blo,
                                    nullptr, nullptr, h1o_h, h1o_l,
                                    h1w_h, h1w_l, creg, biasg);
            }
        } else {
            if (p >= 1) {
                const int s = p - 1;
                unsigned short* h1c_h = plane(s & 1, 0);
                unsigned short* h1c_l = plane(s & 1, 1);
                unsigned short* h2o_h = plane((s + 1) & 1, 2);
                unsigned short* h2o_l = plane((s + 1) & 1, 3);
                unsigned short* h2w_h = plane(s & 1, 2);
                unsigned short* h2w_l = plane(s & 1, 3);
                phase_compute<false>(s, pod, hs, w, lane, x, whi, blo,
                                     h1c_h, h1c_l, h2o_h, h2o_l,
                                     h2w_h, h2w_l, creg, biasg);
            }
        }
        // ---- pod barrier (32 blocks), monotonic counter
        __syncthreads();
        if (tid == 0) {
            __hip_atomic_fetch_add(bar, 1u, __ATOMIC_RELEASE, __HIP_MEMORY_SCOPE_AGENT);
            const unsigned tgt = 32u * (unsigned)(p + 1);
            while (__hip_atomic_load(bar, __ATOMIC_ACQUIRE, __HIP_MEMORY_SCOPE_AGENT) < tgt) {}
        }
        __syncthreads();
    }

    // ---- output projection: member-0 block per pod; final h2 = step 1023 -> parity 1
    if (member == 0) {
        const unsigned short* h2h = plane(1, 2);
        const unsigned short* h2l = plane(1, 3);
        const int r = tid >> 2, part = tid & 3;
        const int row = pod * 64 + r;
        float s = 0.f;
        for (int k = part * 64; k < part * 64 + 64; ++k) {
            float hvv = bf2f(h2h[(size_t)row * Hdim + k]) + bf2f(h2l[(size_t)row * Hdim + k]);
            s += hvv * Wout[k];
        }
        s += __shfl_xor(s, 1);
        s += __shfl_xor(s, 2);
        if (part == 0) out[row] = s + bout[0];
    }
}

extern "C" void kernel_launch(void* const* d_in, const int* in_sizes, int n_in,
                              void* d_out, int out_size, void* d_ws, size_t ws_size,
                              hipStream_t stream)
{
    const float* x    = (const float*)d_in[0];
    const float* W1   = (const float*)d_in[1];
    const float* b1   = (const float*)d_in[2];
    const float* W2   = (const float*)d_in[3];
    const float* b2   = (const float*)d_in[4];
    const float* Wout = (const float*)d_in[5];
    const float* bout = (const float*)d_in[6];

    hipMemsetAsync(d_ws, 0, ZERO_BYTES, stream);
    lstm_persist<<<256, 256, 0, stream>>>(x, W1, b1, W2, b2, Wout, bout,
                                          (float*)d_out ? (float*)d_out : nullptr,
                                          (char*)d_ws);
}

// Round 3
// 14139.139 us; speedup vs baseline: 3.1008x; 1.7012x over previous
//
#include <hip/hip_runtime.h>
#include <math.h>

#define Tlen  1024
#define Din   128
#define Hdim  256

typedef __attribute__((ext_vector_type(8)))  short short8;
typedef __attribute__((ext_vector_type(16))) short short16;
typedef __attribute__((ext_vector_type(4)))  float f32x4;

// ---------------- ws layout (bytes) ----------------
// [0,1024)           : pod barrier counters (pod p at u32 offset p*32 = byte p*128)
// [1024, +1MB)       : parity-1 packed h planes (zeroed): h1 512KB then h2 512KB
//                      element = u32: low16 = bf16-hi, high16 = bf16-lo
// [1049600, +1MB)    : parity-0 packed h planes (written before read)
// [2098176, +768KB)  : W1-lo swizzled, per-hs slab 48 KB
// [2884608, +1MB)    : W2-lo swizzled, per-hs slab 64 KB
#define WS_BAR    0
#define WS_H      1024
#define WS_WLO1   2098176
#define WS_WLO2   2884608
#define ZERO_BYTES (1024 + 1048576)

__device__ __forceinline__ unsigned short f2bf(float f) {
    unsigned u = __float_as_uint(f);
    u += 0x7fffu + ((u >> 16) & 1u);
    return (unsigned short)(u >> 16);
}
__device__ __forceinline__ float bf2f(unsigned short s) {
    return __uint_as_float(((unsigned)s) << 16);
}
__device__ __forceinline__ float sigf(float x) { return 1.0f / (1.0f + __expf(-x)); }
__device__ __forceinline__ float tanh_(float x) {
    x = fminf(fmaxf(x, -15.0f), 15.0f);
    float e = __expf(2.0f * x);
    return (e - 1.0f) / (e + 1.0f);
}

// Load one A fragment (8 packed u32 elems) from an h plane, bypassing L1/L2.
__device__ __forceinline__ void afrag(const unsigned* p, short8& ah, short8& al) {
    union { unsigned long long u[4]; short16 v; } t;
    const unsigned long long* q = (const unsigned long long*)p;
    t.u[0] = __hip_atomic_load(q + 0, __ATOMIC_RELAXED, __HIP_MEMORY_SCOPE_AGENT);
    t.u[1] = __hip_atomic_load(q + 1, __ATOMIC_RELAXED, __HIP_MEMORY_SCOPE_AGENT);
    t.u[2] = __hip_atomic_load(q + 2, __ATOMIC_RELAXED, __HIP_MEMORY_SCOPE_AGENT);
    t.u[3] = __hip_atomic_load(q + 3, __ATOMIC_RELAXED, __HIP_MEMORY_SCOPE_AGENT);
    ah = __builtin_shufflevector(t.v, t.v, 0, 2, 4, 6, 8, 10, 12, 14);
    al = __builtin_shufflevector(t.v, t.v, 1, 3, 5, 7, 9, 11, 13, 15);
}

#define MFMA3(g, AH, AL, BH, BL)                                                   \
    acc[g] = __builtin_amdgcn_mfma_f32_16x16x32_bf16(AH, BH, acc[g], 0, 0, 0);     \
    acc[g] = __builtin_amdgcn_mfma_f32_16x16x32_bf16(AL, BH, acc[g], 0, 0, 0);     \
    acc[g] = __builtin_amdgcn_mfma_f32_16x16x32_bf16(AH, BL, acc[g], 0, 0, 0);

__global__ __launch_bounds__(256, 1) void lstm_persist(
    const float* __restrict__ x,
    const float* __restrict__ W1, const float* __restrict__ b1,
    const float* __restrict__ W2, const float* __restrict__ b2,
    const float* __restrict__ Wout, const float* __restrict__ bout,
    float* __restrict__ out, char* __restrict__ wsb)
{
    __shared__ short8 whi[4096];   // 64 KB: [ks][gate][lane], 16B fragments

    const int tid    = threadIdx.x;
    const int pod    = blockIdx.x & 7;     // likely XCD-local under %8 mapping (perf only)
    const int member = blockIdx.x >> 3;    // 0..31
    const bool is_l1 = (member < 16);
    const int hs     = member & 15;
    const int NKS    = is_l1 ? 12 : 16;
    const float* Wraw = is_l1 ? W1 : W2;
    const float* bias = is_l1 ? b1 : b2;

    short8* blo = (short8*)(wsb + (is_l1 ? (WS_WLO1 + (size_t)hs * 49152)
                                         : (WS_WLO2 + (size_t)hs * 65536)));

    // ---- init: swizzle weight slice into fragment order: hi -> LDS, lo -> ws
    for (int t = tid; t < NKS * 256; t += 256) {
        const int lane = t & 63, g = (t >> 6) & 3, ks = t >> 8;
        const int q = lane >> 4, n = lane & 15;
        const int col = g * 256 + hs * 16 + n;
        short8 hv, lv;
#pragma unroll
        for (int j = 0; j < 8; ++j) {
            float v = Wraw[(size_t)(ks * 32 + q * 8 + j) * 1024 + col];
            unsigned short h = f2bf(v);
            hv[j] = (short)h;
            lv[j] = (short)f2bf(v - bf2f(h));
        }
        whi[t] = hv;
        blo[t] = lv;   // plain store; consumed only by this block (same CU/L2)
    }
    __syncthreads();

    const int w = tid >> 6, lane = tid & 63;
    const int q = lane >> 4, n = lane & 15;
    const int rowA = pod * 64 + w * 16 + n;

    float biasg[4];
#pragma unroll
    for (int g = 0; g < 4; ++g) biasg[g] = bias[g * 256 + hs * 16 + n];

    float creg[4] = {0.f, 0.f, 0.f, 0.f};
    unsigned* bar = (unsigned*)(wsb + WS_BAR) + pod * 32;

    auto plane = [&](int par, int layer) -> unsigned* {
        return (unsigned*)(wsb + WS_H + (size_t)(par ^ 1) * 1048576 + (size_t)layer * 524288);
    };

    for (int p = 0; p <= Tlen; ++p) {
        f32x4 acc[4];
        const bool act_l1 = is_l1 && (p < Tlen);
        const bool act_l2 = (!is_l1) && (p >= 1);

        if (act_l1 || act_l2) {
#pragma unroll
            for (int g = 0; g < 4; ++g) {
                acc[g][0] = biasg[g]; acc[g][1] = biasg[g];
                acc[g][2] = biasg[g]; acc[g][3] = biasg[g];
            }
        }

        // ---- L1 part 1 (x-dependent, no barrier needed): ksteps 0..3
        if (act_l1) {
#pragma unroll
            for (int ks = 0; ks < 4; ++ks) {
                const int kk = ks * 32 + q * 8;
                const float* xp = x + (size_t)rowA * (size_t)(Tlen * Din) + (size_t)p * Din + kk;
                f32x4 v0 = *(const f32x4*)xp;
                f32x4 v1 = *(const f32x4*)(xp + 4);
                float vv[8] = {v0[0], v0[1], v0[2], v0[3], v1[0], v1[1], v1[2], v1[3]};
                short8 ah, al;
#pragma unroll
                for (int j = 0; j < 8; ++j) {
                    unsigned short h = f2bf(vv[j]);
                    ah[j] = (short)h;
                    al[j] = (short)f2bf(vv[j] - bf2f(h));
                }
#pragma unroll
                for (int g = 0; g < 4; ++g) {
                    short8 bh = whi[ks * 256 + g * 64 + lane];
                    short8 bl = blo[ks * 256 + g * 64 + lane];
                    MFMA3(g, ah, al, bh, bl)
                }
            }
        }

        // ---- wait for barrier of phase p-1 (relaxed spin; no cache maintenance)
        if (tid == 0 && p > 0) {
            const unsigned tgt = 32u * (unsigned)p;
            while (__hip_atomic_load(bar, __ATOMIC_RELAXED, __HIP_MEMORY_SCOPE_AGENT) < tgt) {}
        }
        __syncthreads();   // broadcast barrier completion; full memory fence for block

        // ---- L1 part 2: h1[p-1]-dependent ksteps 4..11, epilogue
        if (act_l1) {
            const int s = p;
            const unsigned* h1o = plane((s + 1) & 1, 0);
#pragma unroll
            for (int ks = 4; ks < 12; ++ks) {
                const int kk = ks * 32 + q * 8 - Din;
                short8 ah, al;
                afrag(h1o + (size_t)rowA * Hdim + kk, ah, al);
#pragma unroll
                for (int g = 0; g < 4; ++g) {
                    short8 bh = whi[ks * 256 + g * 64 + lane];
                    short8 bl = blo[ks * 256 + g * 64 + lane];
                    MFMA3(g, ah, al, bh, bl)
                }
            }
            unsigned* op = plane(s & 1, 0);
#pragma unroll
            for (int r = 0; r < 4; ++r) {
                float fg = acc[0][r], ig = acc[1][r], gg = acc[2][r], og = acc[3][r];
                float cn = sigf(fg) * creg[r] + sigf(ig) * tanh_(gg);
                creg[r] = cn;
                float hv = sigf(og) * tanh_(cn);
                const int row = pod * 64 + w * 16 + q * 4 + r;
                const int ci  = hs * 16 + n;
                unsigned short hh = f2bf(hv);
                unsigned short ll = f2bf(hv - bf2f(hh));
                unsigned word = (unsigned)hh | ((unsigned)ll << 16);
                __hip_atomic_store(op + (size_t)row * Hdim + ci, word,
                                   __ATOMIC_RELAXED, __HIP_MEMORY_SCOPE_AGENT);
            }
        }

        // ---- L2: step s=p-1, all ksteps gated on barrier(p-1)
        if (act_l2) {
            const int s = p - 1;
            const unsigned* h1c = plane(s & 1, 0);        // h1[s], produced phase p-1
            const unsigned* h2o = plane((s + 1) & 1, 1);  // h2[s-1], produced phase p-1
#pragma unroll
            for (int ks = 0; ks < 8; ++ks) {
                const int kk = ks * 32 + q * 8;
                short8 ah, al;
                afrag(h1c + (size_t)rowA * Hdim + kk, ah, al);
#pragma unroll
                for (int g = 0; g < 4; ++g) {
                    short8 bh = whi[ks * 256 + g * 64 + lane];
                    short8 bl = blo[ks * 256 + g * 64 + lane];
                    MFMA3(g, ah, al, bh, bl)
                }
            }
#pragma unroll
            for (int ks = 8; ks < 16; ++ks) {
                const int kk = ks * 32 + q * 8 - 256;
                short8 ah, al;
                afrag(h2o + (size_t)rowA * Hdim + kk, ah, al);
#pragma unroll
                for (int g = 0; g < 4; ++g) {
                    short8 bh = whi[ks * 256 + g * 64 + lane];
                    short8 bl = blo[ks * 256 + g * 64 + lane];
                    MFMA3(g, ah, al, bh, bl)
                }
            }
            unsigned* op = plane(s & 1, 1);
#pragma unroll
            for (int r = 0; r < 4; ++r) {
                float fg = acc[0][r], ig = acc[1][r], gg = acc[2][r], og = acc[3][r];
                float cn = sigf(fg) * creg[r] + sigf(ig) * tanh_(gg);
                creg[r] = cn;
                float hv = sigf(og) * tanh_(cn);
                const int row = pod * 64 + w * 16 + q * 4 + r;
                const int ci  = hs * 16 + n;
                unsigned short hh = f2bf(hv);
                unsigned short ll = f2bf(hv - bf2f(hh));
                unsigned word = (unsigned)hh | ((unsigned)ll << 16);
                __hip_atomic_store(op + (size_t)row * Hdim + ci, word,
                                   __ATOMIC_RELAXED, __HIP_MEMORY_SCOPE_AGENT);
            }
        }

        // ---- arrive: __syncthreads drains each wave's vmcnt (write-through stores
        // are at the coherence point), then one relaxed add.
        __syncthreads();
        if (tid == 0) {
            __hip_atomic_fetch_add(bar, 1u, __ATOMIC_RELAXED, __HIP_MEMORY_SCOPE_AGENT);
        }
    }

    // ---- output projection (member-0 blocks): final h2 = step 1023, parity 1
    if (member == 0) {
        if (tid == 0) {
            const unsigned tgt = 32u * (unsigned)(Tlen + 1);
            while (__hip_atomic_load(bar, __ATOMIC_RELAXED, __HIP_MEMORY_SCOPE_AGENT) < tgt) {}
        }
        __syncthreads();
        const unsigned* h2f = plane(1, 1);
        const int r = tid >> 2, part = tid & 3;
        const int row = pod * 64 + r;
        float s = 0.f;
        for (int k = part * 64; k < part * 64 + 64; k += 2) {
            unsigned long long u = __hip_atomic_load(
                (const unsigned long long*)(h2f + (size_t)row * Hdim + k),
                __ATOMIC_RELAXED, __HIP_MEMORY_SCOPE_AGENT);
            unsigned w0 = (unsigned)u, w1 = (unsigned)(u >> 32);
            float hv0 = bf2f((unsigned short)(w0 & 0xffff)) + bf2f((unsigned short)(w0 >> 16));
            float hv1 = bf2f((unsigned short)(w1 & 0xffff)) + bf2f((unsigned short)(w1 >> 16));
            s += hv0 * Wout[k] + hv1 * Wout[k + 1];
        }
        s += __shfl_xor(s, 1);
        s += __shfl_xor(s, 2);
        if (part == 0) out[row] = s + bout[0];
    }
}

extern "C" void kernel_launch(void* const* d_in, const int* in_sizes, int n_in,
                              void* d_out, int out_size, void* d_ws, size_t ws_size,
                              hipStream_t stream)
{
    const float* x    = (const float*)d_in[0];
    const float* W1   = (const float*)d_in[1];
    const float* b1   = (const float*)d_in[2];
    const float* W2   = (const float*)d_in[3];
    const float* b2   = (const float*)d_in[4];
    const float* Wout = (const float*)d_in[5];
    const float* bout = (const float*)d_in[6];

    hipMemsetAsync(d_ws, 0, ZERO_BYTES, stream);
    lstm_persist<<<256, 256, 0, stream>>>(x, W1, b1, W2, b2, Wout, bout,
                                          (float*)d_out, (char*)d_ws);
}